// Round 6
// baseline (162.999 us; speedup 1.0000x reference)
//
#include <hip/hip_runtime.h>
#include <hip/hip_bf16.h>
#include <math.h>

#define BB 8
#define NN 512
#define DD 256
#define BNT 4096   // B*N

typedef __attribute__((ext_vector_type(8))) short short8;
typedef __attribute__((ext_vector_type(4))) float f32x4;

// Workspace layout (float offsets). ~18.2 MB.
#define OFF_S0T   0u         // bf16 [8][256][512]   s0T[b][d][i]
#define OFF_GC    524288u    // bf16 [4096][1536]    Gcat[b*512+j][r*256+d]
#define OFF_WCT   3670016u   // bf16 [256][1536]     WcT[e][r*256+d] = relW[r][d][e]
#define OFF_WBT   3866624u   // bf16 [1024][256]     Wbig^T (c rows, k=d)
#define OFF_BB    3997696u   // fp32 [1024]          h1b|outb
#define OFF_CNT   3998720u   // u16  [4096][8]       per-(b,j) relation counts r=0..5
#define OFF_REL   4015104u   // u8   [8][512][512]   relation codes (self=6)

// d_out layout (floats)
#define OUT0_OFF   0u        // output  [8][512][256]
#define INTERP_OFF 1048576u  // interp  [3][4096]
#define SYM_OFF    1060864u  // symbols [8][512][256]

__device__ __forceinline__ float gelu_exact(float x) {
    return 0.5f * x * (1.0f + erff(x * 0.70710678118654752f));
}

__device__ __forceinline__ ushort f2bf(float x) {
    __hip_bfloat16 h = __float2bfloat16(x);
    union { __hip_bfloat16 b; ushort u; } cv;
    cv.b = h;
    return cv.u;
}

// Async global->LDS DMA, 16B per lane. LDS dest is wave-uniform base +
// lane*16; global src is per-lane.
typedef __attribute__((address_space(3))) unsigned int  lds_u32;
typedef __attribute__((address_space(1))) unsigned int  glb_u32;
__device__ __forceinline__ void gload16(const void* g, void* l) {
    __builtin_amdgcn_global_load_lds((const glb_u32*)g, (lds_u32*)l, 16, 0, 0);
}

// Branch-free classification (reference if/elif priority, applied in reverse).
__device__ __forceinline__ int rel_of(float dx, float dy) {
    int r = (fabsf(dx) < 0.3f && fabsf(dy) < 0.3f) ? 4 : 5;
    r = (dx >  0.5f) ? 3 : r;
    r = (dx < -0.5f) ? 2 : r;
    r = (dy < -0.5f) ? 1 : r;
    r = (dy >  0.5f) ? 0 : r;
    return r;
}

// One-hot bf16 fragment from 8 relation-code bytes: 1.0 where code==rr.
__device__ __forceinline__ short8 onehot8(uint2 cw, unsigned rr) {
    union { ushort u[8]; short8 v; } o;
    unsigned m = rr * 0x01010101u;
    unsigned x = cw.x ^ m, y = cw.y ^ m;
#pragma unroll
    for (int t = 0; t < 4; t++) {
        o.u[t]     = (((x >> (8 * t)) & 255u) == 0u) ? 0x3F80 : 0;
        o.u[t + 4] = (((y >> (8 * t)) & 255u) == 0u) ? 0x3F80 : 0;
    }
    return o.v;
}

// EXACT per-byte zero mask (no cross-byte borrow; bit7 set iff byte==0).
__device__ __forceinline__ unsigned zbyte_mask(unsigned t) {
    return ~(((t & 0x7F7F7F7Fu) + 0x7F7F7F7Fu) | t) & 0x80808080u;
}

// 64x64 tile, 4 waves (2x2). Fragment layout (m89/m91 verified):
// A: m=lane&15, k=quad*8+j; B: n=lane&15, k=quad*8+j;
// C/D: col=lane&15, row=quad*4+reg.
// LDS cell layout [k-octet][row] (16B cells) -> conflict-free b128 reads,
// lane-linear for global_load_lds (chunk = one wave-gload of 1KB).
#define WAVE_IDS()                                             \
    const int lane = tid & 63, w = tid >> 6;                   \
    const int wm = w >> 1, wn = w & 1;                         \
    const int quad = lane >> 4, l15 = lane & 15;               \
    const int sm = tid >> 2, sq = tid & 3;                     \
    (void)sm; (void)sq;

#define ACC_INIT()                                             \
    f32x4 acc[2][2];                                           \
    _Pragma("unroll") for (int mt = 0; mt < 2; mt++)           \
    _Pragma("unroll") for (int nt = 0; nt < 2; nt++)           \
        acc[mt][nt] = (f32x4){0.f, 0.f, 0.f, 0.f};

#define MFMA4(a0, a1, b0, b1)                                                     \
    acc[0][0] = __builtin_amdgcn_mfma_f32_16x16x32_bf16(a0, b0, acc[0][0], 0, 0, 0); \
    acc[0][1] = __builtin_amdgcn_mfma_f32_16x16x32_bf16(a0, b1, acc[0][1], 0, 0, 0); \
    acc[1][0] = __builtin_amdgcn_mfma_f32_16x16x32_bf16(a1, b0, acc[1][0], 0, 0, 0); \
    acc[1][1] = __builtin_amdgcn_mfma_f32_16x16x32_bf16(a1, b1, acc[1][1], 0, 0, 0);

#define MFMA_STEP(Abuf, Bbuf)                                                \
    {                                                                        \
        short8 af[2], bfr[2];                                                \
        _Pragma("unroll")                                                    \
        for (int mt = 0; mt < 2; mt++)                                       \
            af[mt] = *(const short8*)&(Abuf)[(quad * 64 + wm * 32 + mt * 16 + l15) * 8]; \
        _Pragma("unroll")                                                    \
        for (int nt = 0; nt < 2; nt++)                                       \
            bfr[nt] = *(const short8*)&(Bbuf)[(quad * 64 + wn * 32 + nt * 16 + l15) * 8]; \
        MFMA4(af[0], af[1], bfr[0], bfr[1]);                                 \
    }

// ---------------------------------------------------------------- front ---
// prep (0..1535) + gather/transpose (1536..1663, 32 rows/block) +
// classify+counts (1664..2175).
__global__ __launch_bounds__(256) void front_kernel(
    const int* __restrict__ ids, const float* __restrict__ positions,
    const float* __restrict__ symt, const float* __restrict__ layt,
    const float* __restrict__ relW, const float* __restrict__ h1W,
    const float* __restrict__ outW, const float* __restrict__ h1b,
    const float* __restrict__ outb, const float* __restrict__ h2b,
    ushort* __restrict__ WcT, ushort* __restrict__ WbT,
    float* __restrict__ bbig, float* __restrict__ outI,
    float* __restrict__ symOut, ushort* __restrict__ s0T,
    unsigned char* __restrict__ rel, ushort* __restrict__ cnts)
{
    __shared__ float shbuf[32 * 257];   // gather transpose tile / classify px,py
    int blk = blockIdx.x, tid = threadIdx.x;
    if (blk < 1536) {
        int idx = blk * 256 + tid;               // 393216
        {
            int e = idx / 1536, k = idx - e * 1536;
            int r = k >> 8, d = k & 255;
            WcT[idx] = f2bf(relW[(r * DD + d) * DD + e]);
        }
        if (idx < 262144) {
            int c = idx >> 8, d = idx & 255;
            float v;
            if (c < 768) { int r = c >> 8, e = c & 255; v = h1W[(r * DD + d) * DD + e]; }
            else         { v = outW[d * DD + (c - 768)]; }
            WbT[idx] = f2bf(v);
        }
        if (idx < 3 * BNT) outI[idx] = h2b[idx >> 12];
        if (idx < 1024) bbig[idx] = (idx < 768) ? h1b[idx] : outb[idx - 768];
    } else if (blk < 1664) {
        // gather + LDS transpose -> symOut (fp32) and s0T (bf16 [b][d][i])
        int row0 = (blk - 1536) * 32;            // global row
        int b = row0 >> 9, i0 = row0 & 511;
        int rl = tid >> 3, dq = (tid & 7) * 4;
        int row = row0 + rl;
        int id = ids[row];
#pragma unroll
        for (int u = 0; u < 8; u++) {
            int d = dq + u * 32;
            float4 a = *(const float4*)&symt[(size_t)id * DD + d];
            float4 c = *(const float4*)&layt[(size_t)id * DD + d];
            float4 v = {a.x + c.x, a.y + c.y, a.z + c.z, a.w + c.w};
            *(float4*)&symOut[(size_t)row * DD + d] = v;
            shbuf[rl * 257 + d + 0] = v.x;
            shbuf[rl * 257 + d + 1] = v.y;
            shbuf[rl * 257 + d + 2] = v.z;
            shbuf[rl * 257 + d + 3] = v.w;
        }
        __syncthreads();
        int dd = tid;                            // 0..255
        union { ushort u[32]; uint4 q[4]; } pk;
#pragma unroll
        for (int ii = 0; ii < 32; ii++) pk.u[ii] = f2bf(shbuf[ii * 257 + dd]);
        ushort* dst = s0T + ((size_t)(b * DD + dd)) * 512 + i0;
#pragma unroll
        for (int q = 0; q < 4; q++) ((uint4*)dst)[q] = pk.q[q];
    } else {
        float* px = shbuf;
        float* py = shbuf + NN;
        int blk2 = blk - 1664;                   // [0,512)
        int b = blk2 >> 6;
        int j0 = (blk2 & 63) << 3;
        int jl = tid >> 5, sub = tid & 31;       // 8 j's x 32 workers x 16 i's
        for (int i = tid; i < NN; i += 256) {
            float2 p = ((const float2*)positions)[b * NN + i];
            px[i] = p.x; py[i] = p.y;
        }
        __syncthreads();
        int j = j0 + jl;
        float xj = px[j], yj = py[j];
        union { unsigned char u8[16]; unsigned wd[4]; uint4 v; } codes;
#pragma unroll
        for (int t = 0; t < 16; t++) {
            int i = sub * 16 + t;
            int r = rel_of(xj - px[i], yj - py[i]);
            r = (i == j) ? 6 : r;
            codes.u8[t] = (unsigned char)r;
        }
        *(uint4*)&rel[((size_t)(b * NN + j)) * NN + sub * 16] = codes.v;
        // per-(j,r) counts: EXACT zero-byte mask (no cross-byte borrow),
        // then 32-lane reduce.
        int cnt[6];
#pragma unroll
        for (int r = 0; r < 6; r++) {
            unsigned m = (unsigned)r * 0x01010101u;
            int c = 0;
#pragma unroll
            for (int k = 0; k < 4; k++)
                c += __builtin_popcount(zbyte_mask(codes.wd[k] ^ m));
            cnt[r] = c;
        }
#pragma unroll
        for (int r = 0; r < 6; r++) {
            cnt[r] += __shfl_xor(cnt[r], 1);
            cnt[r] += __shfl_xor(cnt[r], 2);
            cnt[r] += __shfl_xor(cnt[r], 4);
            cnt[r] += __shfl_xor(cnt[r], 8);
            cnt[r] += __shfl_xor(cnt[r], 16);
        }
        if (sub == 0) {
            uint4 pq;
            pq.x = (unsigned)cnt[0] | ((unsigned)cnt[1] << 16);
            pq.y = (unsigned)cnt[2] | ((unsigned)cnt[3] << 16);
            pq.z = (unsigned)cnt[4] | ((unsigned)cnt[5] << 16);
            pq.w = 0u;
            *(uint4*)&cnts[((size_t)(b * NN + j)) * 8] = pq;
        }
    }
}

// ------------------------------------------------------------------ aggT --
// G[b][j][r*256+d] = sum_i 1[rel(j,i)=r] * s0[b][i][d]
// A one-hot in-register from codes (L2-hot, 2MB); B = s0T[b] (256KB/batch,
// L2-hot, shared by all 48 blocks of the batch). BK=64, 8 steps, dbuf via
// global_load_lds. Plain bf16 stores (no atomics).
// Grid (4 dt, 8 jt, 48 b*6+r) = 1536 blocks = 6/CU.
__global__ __launch_bounds__(256) void aggT_kernel(
    const unsigned char* __restrict__ rel, const ushort* __restrict__ s0T,
    ushort* __restrict__ Gc)
{
    __shared__ ushort Bls[2][4096];
    int tid = threadIdx.x;
    int z = blockIdx.z;
    int b = z / 6;
    unsigned rr = (unsigned)(z - b * 6);
    int row0 = blockIdx.y * 64;   // j
    int col0 = blockIdx.x * 64;   // d
    WAVE_IDS();
    ACC_INIT();
    // B: 64 d-rows x 64 i (BK); chunk c holds i_local=(c&3)*8+(c>=4)*32;
    // wave w stages {w, w+4}
    const ushort* gB = s0T + ((size_t)(b * DD) + col0 + lane) * 512 + w * 8;
    const unsigned char* gC0 = rel + ((size_t)(b * NN) + row0 + wm * 32 + l15) * NN + quad * 8;
    const unsigned char* gC1 = gC0 + 16 * NN;

#define AGT_STAGE(s, buf)                                     \
    gload16(gB + (s) * 64,      &Bls[buf][ w      * 512]);    \
    gload16(gB + (s) * 64 + 32, &Bls[buf][(w + 4) * 512]);

    uint2 cc[2][2], cn[2][2];
    cc[0][0] = *(const uint2*)(gC0);
    cc[0][1] = *(const uint2*)(gC0 + 32);
    cc[1][0] = *(const uint2*)(gC1);
    cc[1][1] = *(const uint2*)(gC1 + 32);
    AGT_STAGE(0, 0);
    __syncthreads();
#pragma unroll
    for (int s = 0; s < 8; s++) {
        if (s < 7) {
            AGT_STAGE(s + 1, (s + 1) & 1);
            cn[0][0] = *(const uint2*)(gC0 + (s + 1) * 64);
            cn[0][1] = *(const uint2*)(gC0 + (s + 1) * 64 + 32);
            cn[1][0] = *(const uint2*)(gC1 + (s + 1) * 64);
            cn[1][1] = *(const uint2*)(gC1 + (s + 1) * 64 + 32);
        }
#pragma unroll
        for (int h = 0; h < 2; h++) {
            short8 a0 = onehot8(cc[0][h], rr);
            short8 a1 = onehot8(cc[1][h], rr);
            short8 b0 = *(const short8*)&Bls[s & 1][((h * 4 + quad) * 64 + wn * 32 + l15) * 8];
            short8 b1 = *(const short8*)&Bls[s & 1][((h * 4 + quad) * 64 + wn * 32 + 16 + l15) * 8];
            MFMA4(a0, a1, b0, b1);
        }
        if (s < 7) {
            cc[0][0] = cn[0][0]; cc[0][1] = cn[0][1];
            cc[1][0] = cn[1][0]; cc[1][1] = cn[1][1];
        }
        __syncthreads();
    }
#undef AGT_STAGE
#pragma unroll
    for (int mt = 0; mt < 2; mt++)
#pragma unroll
        for (int nt = 0; nt < 2; nt++)
#pragma unroll
            for (int v = 0; v < 4; v++) {
                int j = row0 + wm * 32 + mt * 16 + quad * 4 + v;
                int d = col0 + wn * 32 + nt * 16 + l15;
                Gc[((size_t)(b * NN) + j) * 1536 + rr * 256 + d] =
                    f2bf(acc[mt][nt][v]);
            }
}

// ----------------------------------------------------------------- projC --
// symOut[b*512+j][e] += sum_{r,d} Gc[j][r*256+d] * relW[r][d][e]
//                     + sum_r counts[j][r] * relb[r][e]
// Dense GEMM K=1536 (A=Gcat, B=WcT), BK=128 (12 steps x 16 MFMA), dbuf via
// global_load_lds. Single writer per output (no atomics).
// Grid (4 et, 64 jt) = 256 blocks.
__global__ __launch_bounds__(256) void projC_kernel(
    const ushort* __restrict__ Gc, const ushort* __restrict__ WcT,
    const ushort* __restrict__ cnts, const float* __restrict__ relb,
    float* __restrict__ symOut)
{
    __shared__ ushort Als[2][8192], Bls[2][8192];
    int tid = threadIdx.x;
    int row0 = blockIdx.y * 64;   // global row (b*512+j)
    int col0 = blockIdx.x * 64;   // e
    WAVE_IDS();
    ACC_INIT();
    const ushort* gA = Gc  + (size_t)(row0 + lane) * 1536 + w * 8;
    const ushort* gB = WcT + (size_t)(col0 + lane) * 1536 + w * 8;

#define PJ_STAGE(s, buf)                                                    \
    _Pragma("unroll")                                                       \
    for (int p = 0; p < 4; p++) {                                           \
        gload16(gA + (s) * 128 + p * 32, &Als[buf][(w + p * 4) * 512]);     \
        gload16(gB + (s) * 128 + p * 32, &Bls[buf][(w + p * 4) * 512]);     \
    }

    PJ_STAGE(0, 0);
    __syncthreads();
#pragma unroll
    for (int s = 0; s < 12; s++) {
        if (s < 11) { PJ_STAGE(s + 1, (s + 1) & 1); }
#pragma unroll
        for (int h = 0; h < 4; h++) {
            short8 a0 = *(const short8*)&Als[s & 1][((h * 4 + quad) * 64 + wm * 32 + l15) * 8];
            short8 a1 = *(const short8*)&Als[s & 1][((h * 4 + quad) * 64 + wm * 32 + 16 + l15) * 8];
            short8 b0 = *(const short8*)&Bls[s & 1][((h * 4 + quad) * 64 + wn * 32 + l15) * 8];
            short8 b1 = *(const short8*)&Bls[s & 1][((h * 4 + quad) * 64 + wn * 32 + 16 + l15) * 8];
            MFMA4(a0, a1, b0, b1);
        }
        __syncthreads();
    }
#undef PJ_STAGE
    // epilogue: symOut = s0 + contrib + counts·relb (single writer)
#pragma unroll
    for (int mt = 0; mt < 2; mt++)
#pragma unroll
        for (int v = 0; v < 4; v++) {
            int row = row0 + wm * 32 + mt * 16 + quad * 4 + v;
            const ushort* cp = &cnts[(size_t)row * 8];
            float c0 = cp[0], c1 = cp[1], c2 = cp[2];
            float c3 = cp[3], c4 = cp[4], c5 = cp[5];
#pragma unroll
            for (int nt = 0; nt < 2; nt++) {
                int e = col0 + wn * 32 + nt * 16 + l15;
                float bias = c0 * relb[e]            + c1 * relb[DD + e]
                           + c2 * relb[2 * DD + e]   + c3 * relb[3 * DD + e]
                           + c4 * relb[4 * DD + e]   + c5 * relb[5 * DD + e];
                float* po = &symOut[(size_t)row * DD + e];
                *po = *po + acc[mt][nt][v] + bias;
            }
        }
}

// ----------------------------------------------------------------- gemm2 --
// symOut(fp32 -> bf16 reg-staged) @ Wbig^T; B via global_load_lds.
// Col tiles <768: gelu + fused interp reduce (atomicAdd into outI pre-loaded
// with h2b). Else: out0. Grid (16,64) = 1024 blocks = 4/CU.
__global__ __launch_bounds__(256) void gemm2_kernel(
    const float* __restrict__ symOut, const ushort* __restrict__ WbT,
    const float* __restrict__ bbig, const float* __restrict__ h2W,
    float* __restrict__ out0, float* __restrict__ outI)
{
    __shared__ ushort Als[2][2048], Bls[2][2048];
    int tid = threadIdx.x;
    int row0 = blockIdx.y * 64, col0 = blockIdx.x * 64;
    WAVE_IDS();
    ACC_INIT();
    const float*  gA = symOut + (size_t)(row0 + sm) * DD + sq * 8;   // reg-stage A
    const ushort* gB = WbT + (size_t)(col0 + lane) * DD + w * 8;     // DMA B
    const int lo = (sq * 64 + sm) * 8;

#define G2_STAGE(a0, a1, buf)                                       \
    {                                                               \
        union alignas(16) { ushort u[8]; uint4 v; } am;             \
        am.u[0] = f2bf(a0.x); am.u[1] = f2bf(a0.y);                 \
        am.u[2] = f2bf(a0.z); am.u[3] = f2bf(a0.w);                 \
        am.u[4] = f2bf(a1.x); am.u[5] = f2bf(a1.y);                 \
        am.u[6] = f2bf(a1.z); am.u[7] = f2bf(a1.w);                 \
        *(uint4*)&Als[buf][lo] = am.v;                              \
    }

    float4 a0 = *(const float4*)gA;
    float4 a1 = *(const float4*)(gA + 4);
    gload16(gB, &Bls[0][w * 512]);
    G2_STAGE(a0, a1, 0);
    __syncthreads();
#pragma unroll
    for (int s = 0; s < 8; s++) {
        float4 x = a0, y = a1;
        if (s < 7) {
            x = *(const float4*)(gA + (s + 1) * 32);
            y = *(const float4*)(gA + (s + 1) * 32 + 4);
            gload16(gB + (s + 1) * 32, &Bls[(s + 1) & 1][w * 512]);
        }
        MFMA_STEP(Als[s & 1], Bls[s & 1]);
        if (s < 7) { G2_STAGE(x, y, (s + 1) & 1); }
        __syncthreads();
    }
#undef G2_STAGE
    if (col0 >= 768) {
#pragma unroll
        for (int nt = 0; nt < 2; nt++) {
            int c = col0 + wn * 32 + nt * 16 + l15;
            float bb = bbig[c];
#pragma unroll
            for (int mt = 0; mt < 2; mt++)
#pragma unroll
                for (int v = 0; v < 4; v++) {
                    int row = row0 + wm * 32 + mt * 16 + quad * 4 + v;
                    out0[(size_t)row * DD + (c - 768)] = acc[mt][nt][v] + bb;
                }
        }
    } else {
        int head = col0 >> 8;
        float part[2][4];
#pragma unroll
        for (int mt = 0; mt < 2; mt++)
#pragma unroll
            for (int v = 0; v < 4; v++) part[mt][v] = 0.f;
#pragma unroll
        for (int nt = 0; nt < 2; nt++) {
            int c = col0 + wn * 32 + nt * 16 + l15;
            float bb = bbig[c];
            float w2 = h2W[c];
#pragma unroll
            for (int mt = 0; mt < 2; mt++)
#pragma unroll
                for (int v = 0; v < 4; v++)
                    part[mt][v] += gelu_exact(acc[mt][nt][v] + bb) * w2;
        }
#pragma unroll
        for (int mt = 0; mt < 2; mt++)
#pragma unroll
            for (int v = 0; v < 4; v++) {
                float p = part[mt][v];
                p += __shfl_xor(p, 1); p += __shfl_xor(p, 2);
                p += __shfl_xor(p, 4); p += __shfl_xor(p, 8);
                if (l15 == 0) {
                    int row = row0 + wm * 32 + mt * 16 + quad * 4 + v;
                    atomicAdd(&outI[head * BNT + row], p);
                }
            }
    }
}

// ---------------------------------------------------------------- launch --
extern "C" void kernel_launch(void* const* d_in, const int* in_sizes, int n_in,
                              void* d_out, int out_size, void* d_ws, size_t ws_size,
                              hipStream_t stream)
{
    const int*   ids  = (const int*)d_in[0];
    const float* pos  = (const float*)d_in[1];
    const float* symt = (const float*)d_in[2];
    const float* layt = (const float*)d_in[3];
    const float* relW = (const float*)d_in[4];
    const float* relb = (const float*)d_in[5];
    const float* h1W  = (const float*)d_in[6];
    const float* h1b  = (const float*)d_in[7];
    const float* h2W  = (const float*)d_in[8];
    const float* h2b  = (const float*)d_in[9];
    const float* outW = (const float*)d_in[10];
    const float* outb = (const float*)d_in[11];
    float* out = (float*)d_out;
    float* ws  = (float*)d_ws;

    ushort* s0T  = (ushort*)(ws + OFF_S0T);
    ushort* Gc   = (ushort*)(ws + OFF_GC);
    ushort* WcT  = (ushort*)(ws + OFF_WCT);
    ushort* WbT  = (ushort*)(ws + OFF_WBT);
    float*  bbig = ws + OFF_BB;
    ushort* cnts = (ushort*)(ws + OFF_CNT);
    unsigned char* rel = (unsigned char*)(ws + OFF_REL);

    front_kernel<<<2176, 256, 0, stream>>>(ids, pos, symt, layt, relW, h1W, outW,
                                           h1b, outb, h2b, WcT, WbT, bbig,
                                           out + INTERP_OFF, out + SYM_OFF, s0T,
                                           rel, cnts);
    aggT_kernel<<<dim3(4, 8, 48), 256, 0, stream>>>(rel, s0T, Gc);
    projC_kernel<<<dim3(4, 64), 256, 0, stream>>>(Gc, WcT, cnts, relb,
                                                  out + SYM_OFF);
    gemm2_kernel<<<dim3(16, 64), 256, 0, stream>>>(out + SYM_OFF, WbT,
                                                   bbig, h2W,
                                                   out + OUT0_OFF, out + INTERP_OFF);
}